// Round 2
// baseline (681.190 us; speedup 1.0000x reference)
//
#include <hip/hip_runtime.h>
#include <cstdint>
#include <cmath>

#define B_ 16
#define F_ 256
#define T_ 4096
#define L_ 128
#define TC_ 2048
#define D_ 128
#define M_ 1024
#define NROWS_ 32768  // B_*TC_

#define PA 68   // pitch for 64-wide LDS rows (64+4)
#define PB 132  // pitch for 128-wide LDS rows (128+4)

// ---------------- GEMM1: x[b][t][l] = sum_f in[b][f][t] * w1[l][f] ----------
// tile: 64 t-rows x 128 l-cols, K=F chunks of 32. micro 4x8 (split cols).
__global__ __launch_bounds__(256) void gemm1_kernel(
    const float* __restrict__ in, const float* __restrict__ w1,
    float* __restrict__ x) {
  __shared__ float As[32 * PA];  // [ff][tt]
  __shared__ float Bs[32 * PB];  // [ff][ll]
  const int tid = threadIdx.x;
  const int blk = blockIdx.x;
  const int b = blk >> 6;
  const int t0 = (blk & 63) << 6;
  const int tm = tid & 15;  // l-group: cols tm*4..+3 and 64+tm*4..+3
  const int tr = tid >> 4;  // t-group: rows tr*4..+3
  const float* inb = in + (size_t)b * F_ * T_;
  float acc[4][8];
#pragma unroll
  for (int i = 0; i < 4; ++i)
#pragma unroll
    for (int j = 0; j < 8; ++j) acc[i][j] = 0.f;

  for (int f0 = 0; f0 < F_; f0 += 32) {
    // stage A: 32 f x 64 t, direct (t contiguous), b128 writes
#pragma unroll
    for (int it = 0; it < 2; ++it) {
      int e = tid + it * 256;
      int ff = e >> 4, tq = e & 15;
      float4 v = *(const float4*)(inb + (size_t)(f0 + ff) * T_ + t0 + tq * 4);
      *(float4*)(&As[ff * PA + tq * 4]) = v;
    }
    // stage B: 128 l x 32 f, transpose, 2-way-safe lane map
#pragma unroll
    for (int it = 0; it < 4; ++it) {
      int e = tid + it * 256;
      int llow = e & 15, rest = e >> 4;
      int q = rest & 7, lhigh = rest >> 3;
      int l = lhigh * 16 + llow;
      float4 v = *(const float4*)(w1 + l * F_ + f0 + q * 4);
      Bs[(q * 4 + 0) * PB + l] = v.x;
      Bs[(q * 4 + 1) * PB + l] = v.y;
      Bs[(q * 4 + 2) * PB + l] = v.z;
      Bs[(q * 4 + 3) * PB + l] = v.w;
    }
    __syncthreads();
#pragma unroll
    for (int ff = 0; ff < 32; ++ff) {
      float a[4], w[8];
      *(float4*)&a[0] = *(const float4*)&As[ff * PA + tr * 4];
      *(float4*)&w[0] = *(const float4*)&Bs[ff * PB + tm * 4];
      *(float4*)&w[4] = *(const float4*)&Bs[ff * PB + 64 + tm * 4];
#pragma unroll
      for (int i = 0; i < 4; ++i)
#pragma unroll
        for (int j = 0; j < 8; ++j) acc[i][j] = fmaf(a[i], w[j], acc[i][j]);
    }
    __syncthreads();
  }
  float* xb = x + ((size_t)b * T_ + t0) * L_;
#pragma unroll
  for (int i = 0; i < 4; ++i) {
    float* dst = xb + (size_t)(tr * 4 + i) * L_ + tm * 4;
    *(float4*)(dst) = make_float4(acc[i][0], acc[i][1], acc[i][2], acc[i][3]);
    *(float4*)(dst + 64) = make_float4(acc[i][4], acc[i][5], acc[i][6], acc[i][7]);
  }
}

// ---------------- c2[k*M+m] = ||emb_m||^2 ----------------------------------
__global__ __launch_bounds__(256) void c2_kernel(const float* __restrict__ cbs,
                                                 float* __restrict__ c2) {
  int m = blockIdx.x * 256 + threadIdx.x;  // 0..2047
  const float* row = cbs + (size_t)m * D_;
  float s = 0.f;
#pragma unroll
  for (int d = 0; d < D_; d += 4) {
    float4 v = *(const float4*)(row + d);
    s += v.x * v.x;
    s += v.y * v.y;
    s += v.z * v.z;
    s += v.w * v.w;
  }
  c2[m] = s;
}

// ---------------- VQ: dist + gumbel argmax + gather + index write ----------
// tile: 64 rows x (8 x 128 m), K=D chunks of 32. micro 4x8 split-col.
// score(n,m) = -5*(||e_m||^2 - 2*x_n.e_m) + g[n,m]  (argmax-invariant form)
__global__ __launch_bounds__(256) void vq_kernel(
    const float* __restrict__ x, const float* __restrict__ cbs,
    const float* __restrict__ gum, const float* __restrict__ c2,
    float* __restrict__ vq_feat, float* __restrict__ qinds) {
  __shared__ float smem[32 * PA + 32 * PB];
  __shared__ int widx[64];
  float* Xs = smem;            // xT[dd][r]   32 x 68
  float* Es = smem + 32 * PA;  // embT[dd][mm] 32 x 132
  const int tid = threadIdx.x;
  const int blk = blockIdx.x;
  const int cb = blk >> 9;          // codebook
  const int n0 = (blk & 511) << 6;  // first row of this block (64 rows)
  const int tm = tid & 15;          // m-group
  const int tr = tid >> 4;          // row-group: rows tr*4..+3
  const float* cbp = cbs + (size_t)cb * M_ * D_;
  const float* gp = gum + (size_t)cb * NROWS_ * M_;
  const float* c2p = c2 + cb * M_;

  float best[4];
  int bidx[4];
#pragma unroll
  for (int i = 0; i < 4; ++i) {
    best[i] = -INFINITY;
    bidx[i] = 0;
  }

  for (int mt = 0; mt < 8; ++mt) {
    const int m0 = mt << 7;
    float acc[4][8];
#pragma unroll
    for (int i = 0; i < 4; ++i)
#pragma unroll
      for (int j = 0; j < 8; ++j) acc[i][j] = 0.f;

    for (int d0 = 0; d0 < D_; d0 += 32) {
      const int cf = d0 >> 6;
      const int j0 = d0 & 63;
      // stage xT[dd][r]: 64 rows x 32 d, transpose, 2-way-safe map
#pragma unroll
      for (int it = 0; it < 2; ++it) {
        int e = tid + it * 256;
        int rlow = e & 15, rest = e >> 4;
        int q = rest & 7, rhigh = rest >> 3;
        int r = rhigh * 16 + rlow;
        int n = n0 + r;
        int bb = n >> 11, tc = n & 2047;
        const float* src =
            x + ((size_t)bb * T_ + 2 * tc + cf) * L_ + cb * 64 + j0 + q * 4;
        float4 v = *(const float4*)src;
        Xs[(q * 4 + 0) * PA + r] = v.x;
        Xs[(q * 4 + 1) * PA + r] = v.y;
        Xs[(q * 4 + 2) * PA + r] = v.z;
        Xs[(q * 4 + 3) * PA + r] = v.w;
      }
      // stage embT[dd][mm]: 128 m x 32 d, transpose, 2-way-safe map
#pragma unroll
      for (int it = 0; it < 4; ++it) {
        int e = tid + it * 256;
        int mlow = e & 15, rest = e >> 4;
        int q = rest & 7, mhigh = rest >> 3;
        int mm = mhigh * 16 + mlow;
        const float* src = cbp + (size_t)(m0 + mm) * D_ + d0 + q * 4;
        float4 v = *(const float4*)src;
        Es[(q * 4 + 0) * PB + mm] = v.x;
        Es[(q * 4 + 1) * PB + mm] = v.y;
        Es[(q * 4 + 2) * PB + mm] = v.z;
        Es[(q * 4 + 3) * PB + mm] = v.w;
      }
      __syncthreads();
#pragma unroll
      for (int dd = 0; dd < 32; ++dd) {
        float a[4], w[8];
        *(float4*)&a[0] = *(const float4*)&Xs[dd * PA + tr * 4];
        *(float4*)&w[0] = *(const float4*)&Es[dd * PB + tm * 4];
        *(float4*)&w[4] = *(const float4*)&Es[dd * PB + 64 + tm * 4];
#pragma unroll
        for (int i = 0; i < 4; ++i)
#pragma unroll
          for (int j = 0; j < 8; ++j) acc[i][j] = fmaf(a[i], w[j], acc[i][j]);
      }
      __syncthreads();
    }
    // scores for this m-tile (in-thread m ascending -> strict > keeps first)
    float cc[8];
    *(float4*)&cc[0] = *(const float4*)(c2p + m0 + tm * 4);
    *(float4*)&cc[4] = *(const float4*)(c2p + m0 + 64 + tm * 4);
#pragma unroll
    for (int i = 0; i < 4; ++i) {
      int n = n0 + tr * 4 + i;
      const float* grow = gp + (size_t)n * M_ + m0 + tm * 4;
      float g[8];
      *(float4*)&g[0] = *(const float4*)grow;
      *(float4*)&g[4] = *(const float4*)(grow + 64);
#pragma unroll
      for (int j = 0; j < 8; ++j) {
        float dist = cc[j] - 2.f * acc[i][j];
        float sc = fmaf(-5.f, dist, g[j]);
        int m = (j < 4) ? (m0 + tm * 4 + j) : (m0 + 64 + tm * 4 + j - 4);
        if (sc > best[i]) {
          best[i] = sc;
          bidx[i] = m;
        }
      }
    }
  }
  // block argmax across the 16 m-groups per row (overlay staging LDS)
  float* rbest = smem;                 // [64][17]
  int* ridx = (int*)(smem + 64 * 17);  // [64][17]
#pragma unroll
  for (int i = 0; i < 4; ++i) {
    rbest[(tr * 4 + i) * 17 + tm] = best[i];
    ridx[(tr * 4 + i) * 17 + tm] = bidx[i];
  }
  __syncthreads();
  if (tid < 64) {
    float bv = rbest[tid * 17];
    int bi = ridx[tid * 17];
#pragma unroll
    for (int k = 1; k < 16; ++k) {
      float v = rbest[tid * 17 + k];
      int ii = ridx[tid * 17 + k];
      if (v > bv || (v == bv && ii < bi)) {  // ties -> smallest m (jnp.argmax)
        bv = v;
        bi = ii;
      }
    }
    widx[tid] = bi;
    int n = n0 + tid;
    qinds[(size_t)n * 2 + cb] = (float)bi;
  }
  __syncthreads();
  // gather: vq_feat[b][2tc+cf][cb*64+j] = emb[widx][cf*64+j]
#pragma unroll
  for (int it = 0; it < 8; ++it) {
    int e = tid + it * 256;
    int r = e >> 5, qd = e & 31;
    int wi = widx[r];
    float4 v = *(const float4*)(cbp + (size_t)wi * D_ + qd * 4);
    int cf = qd >> 4;
    int n = n0 + r;
    int bb = n >> 11, tc = n & 2047;
    float* dst =
        vq_feat + ((size_t)bb * T_ + 2 * tc + cf) * L_ + cb * 64 + (qd & 15) * 4;
    *(float4*)dst = v;
  }
}

// ---------------- GEMM2: out[b][f][t] = sum_l vq[b][t][l] * w2[f][l] --------
// tile: 64 f-rows x 128 t-cols, K=L chunks of 32. micro 4x8 split-col.
__global__ __launch_bounds__(256) void gemm2_kernel(
    const float* __restrict__ vq, const float* __restrict__ w2,
    float* __restrict__ out) {
  __shared__ float Ws[32 * PA];  // w2T[ll][ff]  32 x 68
  __shared__ float Vs[32 * PB];  // vqT[ll][tt]  32 x 132
  const int tid = threadIdx.x;
  const int blk = blockIdx.x;
  const int b = blk >> 7;
  const int f0 = ((blk >> 5) & 3) << 6;
  const int t0 = (blk & 31) << 7;
  const int tm = tid & 15;  // t-group
  const int tr = tid >> 4;  // f-group
  const float* vb = vq + (size_t)b * T_ * L_;
  float acc[4][8];
#pragma unroll
  for (int i = 0; i < 4; ++i)
#pragma unroll
    for (int j = 0; j < 8; ++j) acc[i][j] = 0.f;

  for (int l0 = 0; l0 < L_; l0 += 32) {
    // stage w2T[ll][ff]: 64 f x 32 l, transpose, 2-way-safe map
#pragma unroll
    for (int it = 0; it < 2; ++it) {
      int e = tid + it * 256;
      int flow = e & 15, rest = e >> 4;
      int q = rest & 7, fhigh = rest >> 3;
      int f = fhigh * 16 + flow;
      float4 v = *(const float4*)(w2 + (size_t)(f0 + f) * L_ + l0 + q * 4);
      Ws[(q * 4 + 0) * PA + f] = v.x;
      Ws[(q * 4 + 1) * PA + f] = v.y;
      Ws[(q * 4 + 2) * PA + f] = v.z;
      Ws[(q * 4 + 3) * PA + f] = v.w;
    }
    // stage vqT[ll][tt]: 128 t x 32 l, transpose, 2-way-safe map
#pragma unroll
    for (int it = 0; it < 4; ++it) {
      int e = tid + it * 256;
      int tlow = e & 15, rest = e >> 4;
      int q = rest & 7, thigh = rest >> 3;
      int t = thigh * 16 + tlow;
      float4 v = *(const float4*)(vb + (size_t)(t0 + t) * L_ + l0 + q * 4);
      Vs[(q * 4 + 0) * PB + t] = v.x;
      Vs[(q * 4 + 1) * PB + t] = v.y;
      Vs[(q * 4 + 2) * PB + t] = v.z;
      Vs[(q * 4 + 3) * PB + t] = v.w;
    }
    __syncthreads();
#pragma unroll
    for (int ll = 0; ll < 32; ++ll) {
      float a[4], w[8];
      *(float4*)&a[0] = *(const float4*)&Ws[ll * PA + tr * 4];
      *(float4*)&w[0] = *(const float4*)&Vs[ll * PB + tm * 4];
      *(float4*)&w[4] = *(const float4*)&Vs[ll * PB + 64 + tm * 4];
#pragma unroll
      for (int i = 0; i < 4; ++i)
#pragma unroll
        for (int j = 0; j < 8; ++j) acc[i][j] = fmaf(a[i], w[j], acc[i][j]);
    }
    __syncthreads();
  }
  // out[b][f0+tr*4+i][t0 + tm*4 + {0..3}] and +64
  float* ob = out + ((size_t)b * F_ + f0) * T_ + t0;
#pragma unroll
  for (int i = 0; i < 4; ++i) {
    float* dst = ob + (size_t)(tr * 4 + i) * T_ + tm * 4;
    *(float4*)dst = make_float4(acc[i][0], acc[i][1], acc[i][2], acc[i][3]);
    *(float4*)(dst + 64) = make_float4(acc[i][4], acc[i][5], acc[i][6], acc[i][7]);
  }
}

extern "C" void kernel_launch(void* const* d_in, const int* in_sizes, int n_in,
                              void* d_out, int out_size, void* d_ws,
                              size_t ws_size, hipStream_t stream) {
  const float* in = (const float*)d_in[0];
  const float* w1 = (const float*)d_in[1];
  const float* w2 = (const float*)d_in[2];
  const float* cbs = (const float*)d_in[3];
  const float* gum = (const float*)d_in[4];
  float* out = (float*)d_out;
  float* vq_feat = out + 16777216;  // out1 region [B,T,L]
  float* qinds = out + 25165824;    // out2 region [B,TC,K]
  // scratch inside the out0 region: x (8,388,608 floats) + c2 (2048 floats).
  // gemm2 (last kernel) overwrites all of out0, so this is safe.
  float* x = out;
  float* c2 = out + 8388608;

  hipLaunchKernelGGL(gemm1_kernel, dim3(1024), dim3(256), 0, stream, in, w1, x);
  hipLaunchKernelGGL(c2_kernel, dim3(8), dim3(256), 0, stream, cbs, c2);
  hipLaunchKernelGGL(vq_kernel, dim3(1024), dim3(256), 0, stream, x, cbs, gum,
                     c2, vq_feat, qinds);
  hipLaunchKernelGGL(gemm2_kernel, dim3(2048), dim3(256), 0, stream, vq_feat,
                     w2, out);
}